// Round 4
// baseline (319.553 us; speedup 1.0000x reference)
//
#include <hip/hip_runtime.h>
#include <hip/hip_bf16.h>
#include <math.h>

typedef __bf16 bf16x8 __attribute__((ext_vector_type(8)));
typedef float  f32x4  __attribute__((ext_vector_type(4)));
typedef unsigned short ushort_t;
typedef unsigned char  u8;
typedef unsigned int   u32;

#define N_POI 4096
#define NB    8
#define NDAYS 4
#define LSEQ  64
#define NROWS 32   // NB*NDAYS
#define NBINS 102  // 101 intervals + 1 pad/clamp slot
#define KC    3    // global K-split factor (768 blocks = 3 blocks/CU)

static __device__ __forceinline__ u32 bf16bits(float f) {
  u32 x = __float_as_uint(f);
  return ((x + 0x7FFFu + ((x >> 16) & 1u)) >> 16) & 0xFFFFu;  // RTNE
}

static __device__ __forceinline__ float b2f(ushort_t u) {
  return __uint_as_float((u32)u << 16);
}

// ---------------------------------------------------------------------------
// K1: bucketize dm (side='right' == floor(2v)+1) into uint8, plus per-row
//     bucket histograms stored TRANSPOSED: hist[k][row] (coalesced consumer).
// ---------------------------------------------------------------------------
__global__ __launch_bounds__(256) void k_bucket(const float* __restrict__ dm,
                                                u8* __restrict__ bucket,
                                                float* __restrict__ hist) {
  const int row = blockIdx.x, tid = threadIdx.x;
  __shared__ int h[NBINS];
  for (int k = tid; k < NBINS; k += 256) h[k] = 0;
  __syncthreads();
  const float4* drow = (const float4*)(dm + (size_t)row * N_POI);
  u32* brow = (u32*)(bucket + (size_t)row * N_POI);
  for (int it = 0; it < 4; ++it) {
    const int j = it * 256 + tid;
    const float4 v = drow[j];
    const int b0 = min((int)(2.0f * v.x) + 1, 101);
    const int b1 = min((int)(2.0f * v.y) + 1, 101);
    const int b2 = min((int)(2.0f * v.z) + 1, 101);
    const int b3 = min((int)(2.0f * v.w) + 1, 101);
    atomicAdd(&h[b0], 1); atomicAdd(&h[b1], 1);
    atomicAdd(&h[b2], 1); atomicAdd(&h[b3], 1);
    brow[j] = (u32)b0 | ((u32)b1 << 8) | ((u32)b2 << 16) | ((u32)b3 << 24);
  }
  __syncthreads();
  for (int k = tid; k < NBINS; k += 256) hist[(size_t)k * N_POI + row] = (float)h[k];
}

// ---------------------------------------------------------------------------
// K2a: per-sample setup (argsort of ids, last-day spans, bincount/63 weights)
// ---------------------------------------------------------------------------
__global__ __launch_bounds__(64) void k_sample(const int* __restrict__ ids,
                                               const int* __restrict__ seq,
                                               const float* __restrict__ dm,
                                               float* __restrict__ tfp,
                                               u32* __restrict__ tbu,
                                               int* __restrict__ meta) {
  __shared__ int sh_ids[NROWS];
  __shared__ int sh_order[NROWS];
  __shared__ int sh_cnt[NBINS];
  __shared__ int sh_last[LSEQ];
  __shared__ int sh_nb;
  const int tid = threadIdx.x, s = blockIdx.x;
  if (tid < NROWS) sh_ids[tid] = ids[tid];
  for (int k = tid; k < NBINS; k += 64) sh_cnt[k] = 0;
  if (tid == 0) sh_nb = 0;
  __syncthreads();
  if (tid < NROWS) {
    const int my = sh_ids[tid];
    int rank = 0, first = 1;
    for (int j = 0; j < NROWS; ++j) {
      const int v = sh_ids[j];
      if (v < my || (v == my && j < tid)) rank++;
      if (v == my && j < tid) first = 0;
    }
    sh_order[rank] = tid;
    if (first) atomicAdd(&sh_nb, 1);
  }
  __syncthreads();
  const int nb = sh_nb;
  const int days = NROWS / nb;
  if (s == 0) {
    if (tid < NROWS) meta[tid] = sh_order[tid];
    if (tid == 0) meta[NROWS] = days;
  }
  const int lastRow = sh_order[s * days + days - 1];
  sh_last[tid] = seq[lastRow * LSEQ + tid];
  __syncthreads();
  if (tid < LSEQ - 1) {
    const float v = dm[(size_t)(sh_last[tid] - 1) * N_POI + (sh_last[tid + 1] - 1)];
    int si = (int)ceilf(2.0f * v);
    si = min(max(si, 0), 101);
    atomicAdd(&sh_cnt[si], 1);
  }
  __syncthreads();
  const float inv = 1.0f / (float)(LSEQ - 1);
  for (int k = tid; k < 128; k += 64) {
    const float wv = (k < NBINS) ? (float)sh_cnt[k] * inv : 0.0f;
    tfp[s * 128 + k] = wv;
    tbu[s * 128 + k] = bf16bits(wv);
  }
}

// ---------------------------------------------------------------------------
// K2b: rowsum = hist_T·t - t[bucket[i,i]] + 1, r = rsqrt,
//      Y1^T[d][i] = bf16(r_i * poi_emb[i][d]).
// ---------------------------------------------------------------------------
__global__ __launch_bounds__(256) void k_rows(const float* __restrict__ hist,
                                              const float* __restrict__ tfp,
                                              const u8* __restrict__ bucket,
                                              const float* __restrict__ poi,
                                              float* __restrict__ rbuf,
                                              ushort_t* __restrict__ y1t) {
  const int s = blockIdx.y;
  const int i = blockIdx.x * 256 + threadIdx.x;
  __shared__ float tl[NBINS];
  for (int k = threadIdx.x; k < NBINS; k += 256) tl[k] = tfp[s * 128 + k];
  __syncthreads();
  float dot = 0.f;
#pragma unroll 6
  for (int k = 0; k < NBINS; ++k) dot += hist[(size_t)k * N_POI + i] * tl[k];
  const int bii = bucket[(size_t)i * N_POI + i];
  const float ri = rsqrtf(dot - tl[bii] + 1.0f);  // diag W[i,i]=1 override
  rbuf[s * N_POI + i] = ri;
#pragma unroll 8
  for (int d = 0; d < 64; ++d) {
    const float pv = poi[(size_t)(i + 1) * 64 + d];  // poi_emb[i] = poi_weight[i+1]
    y1t[((size_t)s * 64 + d) * N_POI + i] = (ushort_t)bf16bits(ri * pv);
  }
}

// ---------------------------------------------------------------------------
// K3: GCN layer partial GEMM over one K-chunk. A = t[bucket] (diag=1) built
// in-register from bank-replicated LDS LUT (the only LDS use, 13 KB; its
// 2-way lane/lane+32 aliasing shows as SQ_LDS_BANK_CONFLICT but is free).
// B fragments (Y^T) are 16B-contiguous in global (L2/L3-resident) and are
// loaded DIRECTLY to registers, double-buffered one K-tile ahead. The
// per-tile __syncthreads (which drains vmcnt(0)) is what PINS the prefetch:
// without it the compiler sinks the loads to their use point (rounds 1-2,
// VGPR collapsed to 80, 95 us); with it round 3 pipelined correctly.
// Grid (32 rb, KC, 8 s) = 768 blocks -> 3 blocks/CU, 12 waves/CU.
// Epilogue stores raw bf16 partials (r / tanh applied downstream).
// ---------------------------------------------------------------------------
__global__ __launch_bounds__(256, 3) void k_layer(
    const u8* __restrict__ bucket, const u32* __restrict__ tbu,
    const ushort_t* __restrict__ yin, ushort_t* __restrict__ part) {
  const int rb = blockIdx.x, kc = blockIdx.y, s = blockIdx.z;
  const int tid = threadIdx.x;
  const int lane = tid & 63, w = tid >> 6;
  const int loff = tid & 31;

  __shared__ u32 trep[NBINS * 32];  // bank-replicated LUT, 13 KB

  const int gi0 = rb * 128;
  const int r0 = gi0 + w * 32 + (lane & 15);
  const u8* brow0 = bucket + (size_t)r0 * N_POI;
  const u8* brow1 = brow0 + (size_t)16 * N_POI;
  const int kq = (lane >> 4) * 8;

  // B-fragment base: lane's Y^T row + its k-quad; 16B loads at
  // yr0 + nt*16*N_POI + k0 + ks*32 are the exact MFMA B-slices.
  const ushort_t* yr0 =
      yin + (size_t)s * 64 * N_POI + (size_t)(lane & 15) * N_POI + kq;

  const int kt0 = (kc * 64) / KC, kt1 = ((kc + 1) * 64) / KC;  // 21/21/22 tiles

  uint2 bpA[4], bpB[4];
  uint4 ybA[2][4], ybB[2][4];

#define LOADB_(dst, ktv)                                   \
  {                                                        \
    const int _kb = (ktv) * 64;                            \
    dst[0] = *(const uint2*)(brow0 + _kb + kq);            \
    dst[1] = *(const uint2*)(brow0 + _kb + 32 + kq);       \
    dst[2] = *(const uint2*)(brow1 + _kb + kq);            \
    dst[3] = *(const uint2*)(brow1 + _kb + 32 + kq);       \
  }

#define LOADY_(dst, ktv)                                                     \
  {                                                                          \
    const int _ky = (ktv) * 64;                                              \
    _Pragma("unroll") for (int ks = 0; ks < 2; ++ks)                         \
        _Pragma("unroll") for (int nt = 0; nt < 4; ++nt)                     \
            dst[ks][nt] =                                                    \
        *(const uint4*)(yr0 + (size_t)nt * 16 * N_POI + _ky + ks * 32);      \
  }

  // prologue: first tile's loads + trep LUT
  LOADY_(ybA, kt0);
  LOADB_(bpA, kt0);
  for (int idx = tid; idx < NBINS * 32; idx += 256)
    trep[idx] = tbu[s * 128 + (idx >> 5)];

  f32x4 acc[2][4];
#pragma unroll
  for (int mt = 0; mt < 2; ++mt)
#pragma unroll
    for (int nt = 0; nt < 4; ++nt) acc[mt][nt] = (f32x4){0.f, 0.f, 0.f, 0.f};

  __syncthreads();  // trep ready; prologue loads drained (vmcnt(0))

#define BODY_(CB, CY, PB, PY)                                                  \
  {                                                                            \
    const int k0 = kt * 64;                                                    \
    if (kt + 1 < kt1) { LOADY_(PY, kt + 1); LOADB_(PB, kt + 1); }              \
    bf16x8 afr[2][2];                                                          \
    _Pragma("unroll") for (int mt = 0; mt < 2; ++mt) {                         \
      _Pragma("unroll") for (int ks = 0; ks < 2; ++ks) {                       \
        const uint2 bb = CB[mt * 2 + ks];                                      \
        u32 tv[8];                                                             \
        _Pragma("unroll") for (int e = 0; e < 4; ++e) tv[e] =                  \
            trep[((bb.x >> (8 * e)) & 255u) * 32 + loff];                      \
        _Pragma("unroll") for (int e = 0; e < 4; ++e) tv[4 + e] =              \
            trep[((bb.y >> (8 * e)) & 255u) * 32 + loff];                      \
        const u32 de = (u32)(r0 + mt * 16 - (k0 + ks * 32 + kq));              \
        if (de < 8u) { /* diagonal A[i,i] = 1.0 */                             \
          _Pragma("unroll") for (int e = 0; e < 8; ++e)                        \
              if (de == (u32)e) tv[e] = 0x3F80u;                               \
        }                                                                      \
        uint4 pk;                                                              \
        pk.x = tv[0] | (tv[1] << 16);                                          \
        pk.y = tv[2] | (tv[3] << 16);                                          \
        pk.z = tv[4] | (tv[5] << 16);                                          \
        pk.w = tv[6] | (tv[7] << 16);                                          \
        union { uint4 u; bf16x8 v; } cvt;                                      \
        cvt.u = pk;                                                            \
        afr[mt][ks] = cvt.v;                                                   \
      }                                                                        \
    }                                                                          \
    _Pragma("unroll") for (int ks = 0; ks < 2; ++ks) {                         \
      _Pragma("unroll") for (int nt = 0; nt < 4; ++nt) {                       \
        union { uint4 u; bf16x8 v; } bu;                                       \
        bu.u = CY[ks][nt];                                                     \
        acc[0][nt] = __builtin_amdgcn_mfma_f32_16x16x32_bf16(afr[0][ks], bu.v, \
                                                             acc[0][nt], 0, 0, 0); \
        acc[1][nt] = __builtin_amdgcn_mfma_f32_16x16x32_bf16(afr[1][ks], bu.v, \
                                                             acc[1][nt], 0, 0, 0); \
      }                                                                        \
    }                                                                          \
    __syncthreads(); /* drains vmcnt(0): PY/PB landed; pins loads above */     \
  }

  int kt = kt0;
  while (true) {
    BODY_(bpA, ybA, bpB, ybB);
    if (++kt >= kt1) break;
    BODY_(bpB, ybB, bpA, ybA);
    if (++kt >= kt1) break;
  }

#undef BODY_
#undef LOADY_
#undef LOADB_

  // epilogue: raw bf16 partials. C/D layout col = lane&15, row = (lane>>4)*4+reg
#pragma unroll
  for (int mt = 0; mt < 2; ++mt) {
#pragma unroll
    for (int e = 0; e < 4; ++e) {
      const int row = gi0 + w * 32 + mt * 16 + (lane >> 4) * 4 + e;
#pragma unroll
      for (int nt = 0; nt < 4; ++nt) {
        const int col = nt * 16 + (lane & 15);
        part[(((size_t)kc * NB + s) * N_POI + row) * 64 + col] =
            (ushort_t)bf16bits(acc[mt][nt][e]);
      }
    }
  }
}

// ---------------------------------------------------------------------------
// K3b: reduce KC partials for LAYER 1 only: t = tanh(r*x),
// table = poi_emb + t (fp32); y2t^T = bf16(r*t) via LDS transpose.
// (Layer-2 reduce is folded into k_gather.)
// ---------------------------------------------------------------------------
__global__ __launch_bounds__(256) void k_reduce(
    const ushort_t* __restrict__ part, const float* __restrict__ rbuf,
    const float* __restrict__ poi, float* __restrict__ table,
    ushort_t* __restrict__ y2t) {
  const int it = blockIdx.x, s = blockIdx.y, tid = threadIdx.x;
  __shared__ ushort_t Tt[64 * 72];
#pragma unroll
  for (int j = 0; j < 2; ++j) {
    const int s2 = tid + j * 256;
    const int iloc = s2 >> 3, d0 = (s2 & 7) * 8;
    const int i = it * 64 + iloc;
    const size_t po = ((size_t)s * N_POI + i) * 64 + d0;
    uint4 p0 = *(const uint4*)(part + po);
    uint4 p1 = *(const uint4*)(part + (size_t)NB * N_POI * 64 + po);
    uint4 p2 = *(const uint4*)(part + (size_t)2 * NB * N_POI * 64 + po);
    const u32* a0 = (const u32*)&p0;
    const u32* a1 = (const u32*)&p1;
    const u32* a2 = (const u32*)&p2;
    float x[8];
#pragma unroll
    for (int q = 0; q < 4; ++q) {
      x[2 * q]     = __uint_as_float(a0[q] << 16) + __uint_as_float(a1[q] << 16) +
                     __uint_as_float(a2[q] << 16);
      x[2 * q + 1] = __uint_as_float(a0[q] & 0xFFFF0000u) +
                     __uint_as_float(a1[q] & 0xFFFF0000u) +
                     __uint_as_float(a2[q] & 0xFFFF0000u);
    }
    const float ri = rbuf[s * N_POI + i];
    float t[8];
#pragma unroll
    for (int e = 0; e < 8; ++e) t[e] = tanhf(ri * x[e]);
    float* trow = table + po;
    const float* prow = poi + (size_t)(i + 1) * 64 + d0;
    float4 pz0 = *(const float4*)prow;
    float4 pz1 = *(const float4*)(prow + 4);
    float4 o0 = {pz0.x + t[0], pz0.y + t[1], pz0.z + t[2], pz0.w + t[3]};
    float4 o1 = {pz1.x + t[4], pz1.y + t[5], pz1.z + t[6], pz1.w + t[7]};
    *(float4*)trow = o0;
    *(float4*)(trow + 4) = o1;
#pragma unroll
    for (int e = 0; e < 8; ++e)
      Tt[(d0 + e) * 72 + iloc] = (ushort_t)bf16bits(ri * t[e]);
  }
  __syncthreads();
  const int d = tid >> 2, i0 = (tid & 3) * 16;
  uint4 a = *(const uint4*)&Tt[d * 72 + i0];
  uint4 b = *(const uint4*)&Tt[d * 72 + i0 + 8];
  ushort_t* dst = y2t + ((size_t)s * 64 + d) * N_POI + it * 64 + i0;
  *(uint4*)dst = a;
  *(uint4*)(dst + 8) = b;
}

// ---------------------------------------------------------------------------
// K4: gather + fused layer-2 reduce:
// out[r][p][:] = (id==0) ? poi[0]*8
//              : (table_L1[g][id-1] + tanh(r * sum_kc part2)) * 8
// Only gathered rows (<=2048 of 32768) pay the reduce+tanh.
// ---------------------------------------------------------------------------
__global__ __launch_bounds__(256) void k_gather(const int* __restrict__ seq,
                                                const int* __restrict__ meta,
                                                const float* __restrict__ table,
                                                const float* __restrict__ poi,
                                                const ushort_t* __restrict__ part,
                                                const float* __restrict__ rbuf,
                                                float* __restrict__ out) {
  const int r = blockIdx.x;
  const int p = blockIdx.y * 4 + (threadIdx.x >> 6);
  const int d = threadIdx.x & 63;
  const int days = meta[NROWS];
  const int srcrow = meta[r];
  const int g = r / days;
  const int id = seq[srcrow * LSEQ + p];
  float v;
  if (id == 0) {
    v = poi[d];
  } else {
    const size_t po = ((size_t)g * N_POI + (id - 1)) * 64 + d;
    const float x2 = b2f(part[po]) +
                     b2f(part[(size_t)NB * N_POI * 64 + po]) +
                     b2f(part[(size_t)2 * NB * N_POI * 64 + po]);
    v = table[po] + tanhf(rbuf[g * N_POI + (id - 1)] * x2);
  }
  out[((size_t)r * LSEQ + p) * 64 + d] = v * 8.0f;
}

// ---------------------------------------------------------------------------
extern "C" void kernel_launch(void* const* d_in, const int* in_sizes, int n_in,
                              void* d_out, int out_size, void* d_ws, size_t ws_size,
                              hipStream_t stream) {
  (void)in_sizes; (void)n_in; (void)out_size; (void)ws_size;
  const float* poi = (const float*)d_in[0];  // (4097, 64) f32
  const float* dm  = (const float*)d_in[1];  // (4096, 4096) f32
  const int*   seq = (const int*)d_in[2];    // (32, 64) i32
  const int*   ids = (const int*)d_in[3];    // (32,) i32
  // d_in[4]: GCN_layer_num (== 2 per setup_inputs)

  char* ws = (char*)d_ws;
  size_t off = 0;
  auto carve = [&](size_t bytes) {
    char* p = ws + off;
    off += (bytes + 255) & ~(size_t)255;
    return p;
  };
  u8*       bucket = (u8*)carve((size_t)N_POI * N_POI);            // 16.78 MB
  float*    hist   = (float*)carve((size_t)NBINS * N_POI * 4);     // 1.67 MB (transposed)
  float*    tfp    = (float*)carve((size_t)NB * 128 * 4);
  u32*      tbu    = (u32*)carve((size_t)NB * 128 * 4);
  float*    rbuf   = (float*)carve((size_t)NB * N_POI * 4);
  // table (fp32, 8.39MB) aliases y1t (bf16, 4.19MB): y1t dead after k_layer L1;
  // table first written by k_reduce L1 (later in stream). y2t kept separate.
  float*    table  = (float*)carve((size_t)NB * N_POI * 64 * 4);     // 8.39 MB
  ushort_t* y1t    = (ushort_t*)table;
  ushort_t* y2t    = (ushort_t*)carve((size_t)NB * 64 * N_POI * 2);  // 4.19 MB
  ushort_t* part   = (ushort_t*)carve((size_t)KC * NB * N_POI * 64 * 2);  // 12.58 MB
  int*      meta   = (int*)carve(256);

  k_bucket<<<N_POI, 256, 0, stream>>>(dm, bucket, hist);
  k_sample<<<NB, 64, 0, stream>>>(ids, seq, dm, tfp, tbu, meta);
  k_rows<<<dim3(16, NB), 256, 0, stream>>>(hist, tfp, bucket, poi, rbuf, y1t);
  k_layer<<<dim3(32, KC, NB), 256, 0, stream>>>(bucket, tbu, y1t, part);
  k_reduce<<<dim3(64, NB), 256, 0, stream>>>(part, rbuf, poi, table, y2t);
  k_layer<<<dim3(32, KC, NB), 256, 0, stream>>>(bucket, tbu, y2t, part);
  k_gather<<<dim3(NROWS, 16), 256, 0, stream>>>(seq, meta, table, poi, part, rbuf,
                                                (float*)d_out);
}

// Round 5
// 206.297 us; speedup vs baseline: 1.5490x; 1.5490x over previous
//
#include <hip/hip_runtime.h>
#include <hip/hip_bf16.h>
#include <math.h>

typedef __bf16 bf16x8 __attribute__((ext_vector_type(8)));
typedef float  f32x4  __attribute__((ext_vector_type(4)));
typedef unsigned short ushort_t;
typedef unsigned char  u8;
typedef unsigned int   u32;

#define N_POI 4096
#define NB    8
#define NDAYS 4
#define LSEQ  64
#define NROWS 32   // NB*NDAYS
#define NBINS 102  // 101 intervals + 1 pad/clamp slot
#define KC    3    // global K-split factor (768 blocks = 3 blocks/CU)

static __device__ __forceinline__ u32 bf16bits(float f) {
  u32 x = __float_as_uint(f);
  return ((x + 0x7FFFu + ((x >> 16) & 1u)) >> 16) & 0xFFFFu;  // RTNE
}

static __device__ __forceinline__ float b2f(ushort_t u) {
  return __uint_as_float((u32)u << 16);
}

// async 16B global -> LDS (linear dest, per-lane source)
static __device__ __forceinline__ void gload16(void* lds, const void* g) {
  __builtin_amdgcn_global_load_lds(
      (const __attribute__((address_space(1))) u32*)g,
      (__attribute__((address_space(3))) u32*)lds, 16, 0, 0);
}

// ---------------------------------------------------------------------------
// K2a (runs FIRST): per-sample setup (argsort of ids, last-day spans,
// bincount/63 weights). Only reads dm/seq/ids.
// ---------------------------------------------------------------------------
__global__ __launch_bounds__(64) void k_sample(const int* __restrict__ ids,
                                               const int* __restrict__ seq,
                                               const float* __restrict__ dm,
                                               float* __restrict__ tfp,
                                               u32* __restrict__ tbu,
                                               int* __restrict__ meta) {
  __shared__ int sh_ids[NROWS];
  __shared__ int sh_order[NROWS];
  __shared__ int sh_cnt[NBINS];
  __shared__ int sh_last[LSEQ];
  __shared__ int sh_nb;
  const int tid = threadIdx.x, s = blockIdx.x;
  if (tid < NROWS) sh_ids[tid] = ids[tid];
  for (int k = tid; k < NBINS; k += 64) sh_cnt[k] = 0;
  if (tid == 0) sh_nb = 0;
  __syncthreads();
  if (tid < NROWS) {
    const int my = sh_ids[tid];
    int rank = 0, first = 1;
    for (int j = 0; j < NROWS; ++j) {
      const int v = sh_ids[j];
      if (v < my || (v == my && j < tid)) rank++;
      if (v == my && j < tid) first = 0;
    }
    sh_order[rank] = tid;
    if (first) atomicAdd(&sh_nb, 1);
  }
  __syncthreads();
  const int nb = sh_nb;
  const int days = NROWS / nb;
  if (s == 0) {
    if (tid < NROWS) meta[tid] = sh_order[tid];
    if (tid == 0) meta[NROWS] = days;
  }
  const int lastRow = sh_order[s * days + days - 1];
  sh_last[tid] = seq[lastRow * LSEQ + tid];
  __syncthreads();
  if (tid < LSEQ - 1) {
    const float v = dm[(size_t)(sh_last[tid] - 1) * N_POI + (sh_last[tid + 1] - 1)];
    int si = (int)ceilf(2.0f * v);
    si = min(max(si, 0), 101);
    atomicAdd(&sh_cnt[si], 1);
  }
  __syncthreads();
  const float inv = 1.0f / (float)(LSEQ - 1);
  for (int k = tid; k < 128; k += 64) {
    const float wv = (k < NBINS) ? (float)sh_cnt[k] * inv : 0.0f;
    tfp[s * 128 + k] = wv;
    tbu[s * 128 + k] = bf16bits(wv);
  }
}

// ---------------------------------------------------------------------------
// K1 (fused): bucketize dm row (side='right' == floor(2v)+1) into uint8,
// build the row histogram in LDS (2-way split to halve atomic contention),
// then FUSE the per-sample rowsum: dot_s = sum_k h[k]*t_s[k], diag byte
// captured in-block, rbuf[s][row] = rsqrt(dot - t_s[bii] + 1).
// Eliminates the hist buffer (1.7MB write + 13.4MB re-read) and k_rows' dot.
// ---------------------------------------------------------------------------
__global__ __launch_bounds__(256) void k_bucket(const float* __restrict__ dm,
                                                const float* __restrict__ tfp,
                                                u8* __restrict__ bucket,
                                                float* __restrict__ rbuf) {
  const int row = blockIdx.x, tid = threadIdx.x;
  __shared__ int h[2][NBINS];
  __shared__ float tl[NB][NBINS];
  __shared__ int sh_bii;
  for (int k = tid; k < 2 * NBINS; k += 256) ((int*)h)[k] = 0;
  __syncthreads();
  const float4* drow = (const float4*)(dm + (size_t)row * N_POI);
  u32* brow = (u32*)(bucket + (size_t)row * N_POI);
  int* hp = h[tid >> 7];
  const int jdiag = row >> 2;
  for (int it = 0; it < 4; ++it) {
    const int j = it * 256 + tid;
    const float4 v = drow[j];
    const int b0 = min((int)(2.0f * v.x) + 1, 101);
    const int b1 = min((int)(2.0f * v.y) + 1, 101);
    const int b2 = min((int)(2.0f * v.z) + 1, 101);
    const int b3 = min((int)(2.0f * v.w) + 1, 101);
    atomicAdd(&hp[b0], 1); atomicAdd(&hp[b1], 1);
    atomicAdd(&hp[b2], 1); atomicAdd(&hp[b3], 1);
    const u32 pk = (u32)b0 | ((u32)b1 << 8) | ((u32)b2 << 16) | ((u32)b3 << 24);
    if (j == jdiag) sh_bii = (int)((pk >> (8 * (row & 3))) & 255u);
    brow[j] = pk;
  }
  // stage t tables (8 x 102 floats) while histogram finishes
  for (int idx = tid; idx < NB * NBINS; idx += 256)
    tl[idx / NBINS][idx % NBINS] = tfp[(idx / NBINS) * 128 + (idx % NBINS)];
  __syncthreads();
  for (int k = tid; k < NBINS; k += 256) h[0][k] += h[1][k];
  __syncthreads();
  // 32 lanes per sample: dot_s = sum_k h[k] * t_s[k]
  const int s = tid >> 5, ln = tid & 31;
  float dot = 0.f;
  for (int k = ln; k < NBINS; k += 32) dot += (float)h[0][k] * tl[s][k];
#pragma unroll
  for (int off = 16; off >= 1; off >>= 1) dot += __shfl_down(dot, off, 32);
  if (ln == 0) {
    const float ri = rsqrtf(dot - tl[s][sh_bii] + 1.0f);  // diag W[i,i]=1
    rbuf[s * N_POI + row] = ri;
  }
}

// ---------------------------------------------------------------------------
// K2b (slimmed): Y1^T[d][i] = bf16(r_i * poi_emb[i][d]). rbuf from k_bucket.
// ---------------------------------------------------------------------------
__global__ __launch_bounds__(256) void k_rows(const float* __restrict__ rbuf,
                                              const float* __restrict__ poi,
                                              ushort_t* __restrict__ y1t) {
  const int s = blockIdx.y;
  const int i = blockIdx.x * 256 + threadIdx.x;
  const float ri = rbuf[s * N_POI + i];
#pragma unroll 8
  for (int d = 0; d < 64; ++d) {
    const float pv = poi[(size_t)(i + 1) * 64 + d];  // poi_emb[i] = poi_weight[i+1]
    y1t[((size_t)s * 64 + d) * N_POI + i] = (ushort_t)bf16bits(ri * pv);
  }
}

// ---------------------------------------------------------------------------
// K3: GCN layer partial GEMM over one K-chunk. A = t[bucket] (diag=1) built
// in-register from bank-replicated LDS LUT. Y^T staged in LDS via
// global_load_lds (width 16, DMA, no VGPR round-trip), DOUBLE-BUFFERED with
// ONE barrier per tile. The barrier pins the pipeline BECAUSE the staging
// writes LDS (rounds 1/2/4 proved plain register loads get sunk past
// __syncthreads; VGPR count ~56 here vs 80 when sunk). LDS reads are
// XOR-swizzled via pre-swizzled GLOBAL source column.
// Grid (32 rb, KC, 8 s) = 768 blocks -> 3 blocks/CU, 12 waves/CU.
// Epilogue stores raw bf16 partials (r / tanh applied downstream).
// ---------------------------------------------------------------------------
__global__ __launch_bounds__(256, 3) void k_layer(
    const u8* __restrict__ bucket, const u32* __restrict__ tbu,
    const ushort_t* __restrict__ yin, ushort_t* __restrict__ part) {
  const int rb = blockIdx.x, kc = blockIdx.y, s = blockIdx.z;
  const int tid = threadIdx.x;
  const int lane = tid & 63, w = tid >> 6;
  const int loff = tid & 31;

  __shared__ u32 trep[NBINS * 32];       // bank-replicated LUT, 13 KB
  __shared__ ushort_t Ybuf[2][64 * 64];  // 2 x 8 KB Y^T tiles, row stride 128B

  const int gi0 = rb * 128;
  const int r0 = gi0 + w * 32 + (lane & 15);
  const u8* brow0 = bucket + (size_t)r0 * N_POI;
  const u8* brow1 = brow0 + (size_t)16 * N_POI;
  const int kq = (lane >> 4) * 8;

  const ushort_t* ybase = yin + (size_t)s * 64 * N_POI;

  // staging source (pre-swizzled column): thread covers LDS rows tid>>3 and
  // 32+(tid>>3), 16B at byte (tid&7)*16 of the 128B row.
  // perm(r) = (r&7) ^ ((r>>3)&1); LDS(r,b) holds Y(r, b ^ perm(r)<<4).
  const int d0s = tid >> 3, d1s = 32 + d0s;
  const int bly = (tid & 7) * 16;
  const int sw0 = bly ^ (((d0s & 7) ^ ((d0s >> 3) & 1)) << 4);
  const int sw1 = bly ^ (((d1s & 7) ^ ((d1s >> 3) & 1)) << 4);
  const char* gsrc0 = (const char*)(ybase + (size_t)d0s * N_POI) + sw0;
  const char* gsrc1 = (const char*)(ybase + (size_t)d1s * N_POI) + sw1;

  const int kt0 = (kc * 64) / KC, kt1 = ((kc + 1) * 64) / KC;  // 21/21/22 tiles

  uint2 bpA[4], bpB[4];

#define LOADB_(dst, ktv)                                   \
  {                                                        \
    const int _kb = (ktv) * 64;                            \
    dst[0] = *(const uint2*)(brow0 + _kb + kq);            \
    dst[1] = *(const uint2*)(brow0 + _kb + 32 + kq);       \
    dst[2] = *(const uint2*)(brow1 + _kb + kq);            \
    dst[3] = *(const uint2*)(brow1 + _kb + 32 + kq);       \
  }

#define STAGE_(bufi, ktv)                                  \
  {                                                        \
    const size_t _kb = (size_t)(ktv) * 128;                \
    char* _lb = (char*)&Ybuf[bufi][0] + tid * 16;          \
    gload16(_lb, gsrc0 + _kb);                             \
    gload16(_lb + 4096, gsrc1 + _kb);                      \
  }

  // prologue: stage first tile + first bucket bytes + trep LUT
  STAGE_(0, kt0);
  LOADB_(bpA, kt0);
  for (int idx = tid; idx < NBINS * 32; idx += 256)
    trep[idx] = tbu[s * 128 + (idx >> 5)];

  f32x4 acc[2][4];
#pragma unroll
  for (int mt = 0; mt < 2; ++mt)
#pragma unroll
    for (int nt = 0; nt < 4; ++nt) acc[mt][nt] = (f32x4){0.f, 0.f, 0.f, 0.f};

  asm volatile("s_waitcnt vmcnt(0)" ::: "memory");
  __syncthreads();  // trep + stage(kt0) ready

#define BODY_(CB, PB, CUR)                                                     \
  {                                                                            \
    const int k0 = kt * 64;                                                    \
    if (kt + 1 < kt1) { STAGE_((CUR) ^ 1, kt + 1); LOADB_(PB, kt + 1); }       \
    bf16x8 afr[2][2];                                                          \
    _Pragma("unroll") for (int mt = 0; mt < 2; ++mt) {                         \
      _Pragma("unroll") for (int ks = 0; ks < 2; ++ks) {                       \
        const uint2 bb = CB[mt * 2 + ks];                                      \
        u32 tv[8];                                                             \
        _Pragma("unroll") for (int e = 0; e < 4; ++e) tv[e] =                  \
            trep[((bb.x >> (8 * e)) & 255u) * 32 + loff];                      \
        _Pragma("unroll") for (int e = 0; e < 4; ++e) tv[4 + e] =              \
            trep[((bb.y >> (8 * e)) & 255u) * 32 + loff];                      \
        const u32 de = (u32)(r0 + mt * 16 - (k0 + ks * 32 + kq));              \
        if (de < 8u) { /* diagonal A[i,i] = 1.0 */                             \
          _Pragma("unroll") for (int e = 0; e < 8; ++e)                        \
              if (de == (u32)e) tv[e] = 0x3F80u;                               \
        }                                                                      \
        uint4 pk;                                                              \
        pk.x = tv[0] | (tv[1] << 16);                                          \
        pk.y = tv[2] | (tv[3] << 16);                                          \
        pk.z = tv[4] | (tv[5] << 16);                                          \
        pk.w = tv[6] | (tv[7] << 16);                                          \
        union { uint4 u; bf16x8 v; } cvt;                                      \
        cvt.u = pk;                                                            \
        afr[mt][ks] = cvt.v;                                                   \
      }                                                                        \
    }                                                                          \
    const char* _yb = (const char*)&Ybuf[CUR][0];                              \
    _Pragma("unroll") for (int ks = 0; ks < 2; ++ks) {                         \
      _Pragma("unroll") for (int nt = 0; nt < 4; ++nt) {                       \
        const int rY = nt * 16 + (lane & 15);                                  \
        const int pm = (rY & 7) ^ ((rY >> 3) & 1);                             \
        const int la = rY * 128 + (((ks * 4 + (lane >> 4)) ^ pm) << 4);        \
        union { uint4 u; bf16x8 v; } bu;                                       \
        bu.u = *(const uint4*)(_yb + la);                                      \
        acc[0][nt] = __builtin_amdgcn_mfma_f32_16x16x32_bf16(afr[0][ks], bu.v, \
                                                             acc[0][nt], 0, 0, 0); \
        acc[1][nt] = __builtin_amdgcn_mfma_f32_16x16x32_bf16(afr[1][ks], bu.v, \
                                                             acc[1][nt], 0, 0, 0); \
      }                                                                        \
    }                                                                          \
    asm volatile("s_waitcnt vmcnt(0)" ::: "memory");                           \
    __syncthreads(); /* stage(kt+1) landed; buf[CUR] reads done for all */     \
  }

  int kt = kt0;
  while (true) {
    BODY_(bpA, bpB, 0);
    if (++kt >= kt1) break;
    BODY_(bpB, bpA, 1);
    if (++kt >= kt1) break;
  }

#undef BODY_
#undef STAGE_
#undef LOADB_

  // epilogue: raw bf16 partials. C/D layout col = lane&15, row = (lane>>4)*4+reg
#pragma unroll
  for (int mt = 0; mt < 2; ++mt) {
#pragma unroll
    for (int e = 0; e < 4; ++e) {
      const int row = gi0 + w * 32 + mt * 16 + (lane >> 4) * 4 + e;
#pragma unroll
      for (int nt = 0; nt < 4; ++nt) {
        const int col = nt * 16 + (lane & 15);
        part[(((size_t)kc * NB + s) * N_POI + row) * 64 + col] =
            (ushort_t)bf16bits(acc[mt][nt][e]);
      }
    }
  }
}

// ---------------------------------------------------------------------------
// K3b: reduce KC partials for LAYER 1 only: t = tanh(r*x),
// table = poi_emb + t (fp32); y2t^T = bf16(r*t) via LDS transpose.
// (Layer-2 reduce is folded into k_gather.)
// ---------------------------------------------------------------------------
__global__ __launch_bounds__(256) void k_reduce(
    const ushort_t* __restrict__ part, const float* __restrict__ rbuf,
    const float* __restrict__ poi, float* __restrict__ table,
    ushort_t* __restrict__ y2t) {
  const int it = blockIdx.x, s = blockIdx.y, tid = threadIdx.x;
  __shared__ ushort_t Tt[64 * 72];
#pragma unroll
  for (int j = 0; j < 2; ++j) {
    const int s2 = tid + j * 256;
    const int iloc = s2 >> 3, d0 = (s2 & 7) * 8;
    const int i = it * 64 + iloc;
    const size_t po = ((size_t)s * N_POI + i) * 64 + d0;
    uint4 p0 = *(const uint4*)(part + po);
    uint4 p1 = *(const uint4*)(part + (size_t)NB * N_POI * 64 + po);
    uint4 p2 = *(const uint4*)(part + (size_t)2 * NB * N_POI * 64 + po);
    const u32* a0 = (const u32*)&p0;
    const u32* a1 = (const u32*)&p1;
    const u32* a2 = (const u32*)&p2;
    float x[8];
#pragma unroll
    for (int q = 0; q < 4; ++q) {
      x[2 * q]     = __uint_as_float(a0[q] << 16) + __uint_as_float(a1[q] << 16) +
                     __uint_as_float(a2[q] << 16);
      x[2 * q + 1] = __uint_as_float(a0[q] & 0xFFFF0000u) +
                     __uint_as_float(a1[q] & 0xFFFF0000u) +
                     __uint_as_float(a2[q] & 0xFFFF0000u);
    }
    const float ri = rbuf[s * N_POI + i];
    float t[8];
#pragma unroll
    for (int e = 0; e < 8; ++e) t[e] = tanhf(ri * x[e]);
    float* trow = table + po;
    const float* prow = poi + (size_t)(i + 1) * 64 + d0;
    float4 pz0 = *(const float4*)prow;
    float4 pz1 = *(const float4*)(prow + 4);
    float4 o0 = {pz0.x + t[0], pz0.y + t[1], pz0.z + t[2], pz0.w + t[3]};
    float4 o1 = {pz1.x + t[4], pz1.y + t[5], pz1.z + t[6], pz1.w + t[7]};
    *(float4*)trow = o0;
    *(float4*)(trow + 4) = o1;
#pragma unroll
    for (int e = 0; e < 8; ++e)
      Tt[(d0 + e) * 72 + iloc] = (ushort_t)bf16bits(ri * t[e]);
  }
  __syncthreads();
  const int d = tid >> 2, i0 = (tid & 3) * 16;
  uint4 a = *(const uint4*)&Tt[d * 72 + i0];
  uint4 b = *(const uint4*)&Tt[d * 72 + i0 + 8];
  ushort_t* dst = y2t + ((size_t)s * 64 + d) * N_POI + it * 64 + i0;
  *(uint4*)dst = a;
  *(uint4*)(dst + 8) = b;
}

// ---------------------------------------------------------------------------
// K4: gather + fused layer-2 reduce:
// out[r][p][:] = (id==0) ? poi[0]*8
//              : (table_L1[g][id-1] + tanh(r * sum_kc part2)) * 8
// Only gathered rows (<=2048 of 32768) pay the reduce+tanh.
// ---------------------------------------------------------------------------
__global__ __launch_bounds__(256) void k_gather(const int* __restrict__ seq,
                                                const int* __restrict__ meta,
                                                const float* __restrict__ table,
                                                const float* __restrict__ poi,
                                                const ushort_t* __restrict__ part,
                                                const float* __restrict__ rbuf,
                                                float* __restrict__ out) {
  const int r = blockIdx.x;
  const int p = blockIdx.y * 4 + (threadIdx.x >> 6);
  const int d = threadIdx.x & 63;
  const int days = meta[NROWS];
  const int srcrow = meta[r];
  const int g = r / days;
  const int id = seq[srcrow * LSEQ + p];
  float v;
  if (id == 0) {
    v = poi[d];
  } else {
    const size_t po = ((size_t)g * N_POI + (id - 1)) * 64 + d;
    const float x2 = b2f(part[po]) +
                     b2f(part[(size_t)NB * N_POI * 64 + po]) +
                     b2f(part[(size_t)2 * NB * N_POI * 64 + po]);
    v = table[po] + tanhf(rbuf[g * N_POI + (id - 1)] * x2);
  }
  out[((size_t)r * LSEQ + p) * 64 + d] = v * 8.0f;
}

// ---------------------------------------------------------------------------
extern "C" void kernel_launch(void* const* d_in, const int* in_sizes, int n_in,
                              void* d_out, int out_size, void* d_ws, size_t ws_size,
                              hipStream_t stream) {
  (void)in_sizes; (void)n_in; (void)out_size; (void)ws_size;
  const float* poi = (const float*)d_in[0];  // (4097, 64) f32
  const float* dm  = (const float*)d_in[1];  // (4096, 4096) f32
  const int*   seq = (const int*)d_in[2];    // (32, 64) i32
  const int*   ids = (const int*)d_in[3];    // (32,) i32
  // d_in[4]: GCN_layer_num (== 2 per setup_inputs)

  char* ws = (char*)d_ws;
  size_t off = 0;
  auto carve = [&](size_t bytes) {
    char* p = ws + off;
    off += (bytes + 255) & ~(size_t)255;
    return p;
  };
  u8*       bucket = (u8*)carve((size_t)N_POI * N_POI);            // 16.78 MB
  float*    tfp    = (float*)carve((size_t)NB * 128 * 4);
  u32*      tbu    = (u32*)carve((size_t)NB * 128 * 4);
  float*    rbuf   = (float*)carve((size_t)NB * N_POI * 4);
  // table (fp32, 8.39MB) aliases y1t (bf16, 4.19MB): y1t dead after k_layer L1;
  // table first written by k_reduce L1 (later in stream). y2t kept separate.
  float*    table  = (float*)carve((size_t)NB * N_POI * 64 * 4);     // 8.39 MB
  ushort_t* y1t    = (ushort_t*)table;
  ushort_t* y2t    = (ushort_t*)carve((size_t)NB * 64 * N_POI * 2);  // 4.19 MB
  ushort_t* part   = (ushort_t*)carve((size_t)KC * NB * N_POI * 64 * 2);  // 12.58 MB
  int*      meta   = (int*)carve(256);

  k_sample<<<NB, 64, 0, stream>>>(ids, seq, dm, tfp, tbu, meta);
  k_bucket<<<N_POI, 256, 0, stream>>>(dm, tfp, bucket, rbuf);
  k_rows<<<dim3(16, NB), 256, 0, stream>>>(rbuf, poi, y1t);
  k_layer<<<dim3(32, KC, NB), 256, 0, stream>>>(bucket, tbu, y1t, part);
  k_reduce<<<dim3(64, NB), 256, 0, stream>>>(part, rbuf, poi, table, y2t);
  k_layer<<<dim3(32, KC, NB), 256, 0, stream>>>(bucket, tbu, y2t, part);
  k_gather<<<dim3(NROWS, 16), 256, 0, stream>>>(seq, meta, table, poi, part, rbuf,
                                                (float*)d_out);
}

// Round 6
// 185.197 us; speedup vs baseline: 1.7255x; 1.1139x over previous
//
#include <hip/hip_runtime.h>
#include <hip/hip_bf16.h>
#include <math.h>

typedef __bf16 bf16x8 __attribute__((ext_vector_type(8)));
typedef float  f32x4  __attribute__((ext_vector_type(4)));
typedef unsigned short ushort_t;
typedef unsigned char  u8;
typedef unsigned int   u32;

#define N_POI 4096
#define NB    8
#define NDAYS 4
#define LSEQ  64
#define NROWS 32   // NB*NDAYS
#define NBINS 102  // 101 intervals + 1 pad/clamp slot
#define KC    6    // global K-split factor (32 rb x 6 kc x 4 pairs = 768 blocks)

static __device__ __forceinline__ u32 bf16bits(float f) {
  u32 x = __float_as_uint(f);
  return ((x + 0x7FFFu + ((x >> 16) & 1u)) >> 16) & 0xFFFFu;  // RTNE
}

static __device__ __forceinline__ float b2f(ushort_t u) {
  return __uint_as_float((u32)u << 16);
}

// async 16B global -> LDS (linear dest, per-lane source)
static __device__ __forceinline__ void gload16(void* lds, const void* g) {
  __builtin_amdgcn_global_load_lds(
      (const __attribute__((address_space(1))) u32*)g,
      (__attribute__((address_space(3))) u32*)lds, 16, 0, 0);
}

// ---------------------------------------------------------------------------
// K2a (runs FIRST): per-sample setup (argsort of ids, last-day spans,
// bincount/63 weights). Only reads dm/seq/ids.
// ---------------------------------------------------------------------------
__global__ __launch_bounds__(64) void k_sample(const int* __restrict__ ids,
                                               const int* __restrict__ seq,
                                               const float* __restrict__ dm,
                                               float* __restrict__ tfp,
                                               u32* __restrict__ tbu,
                                               int* __restrict__ meta) {
  __shared__ int sh_ids[NROWS];
  __shared__ int sh_order[NROWS];
  __shared__ int sh_cnt[NBINS];
  __shared__ int sh_last[LSEQ];
  __shared__ int sh_nb;
  const int tid = threadIdx.x, s = blockIdx.x;
  if (tid < NROWS) sh_ids[tid] = ids[tid];
  for (int k = tid; k < NBINS; k += 64) sh_cnt[k] = 0;
  if (tid == 0) sh_nb = 0;
  __syncthreads();
  if (tid < NROWS) {
    const int my = sh_ids[tid];
    int rank = 0, first = 1;
    for (int j = 0; j < NROWS; ++j) {
      const int v = sh_ids[j];
      if (v < my || (v == my && j < tid)) rank++;
      if (v == my && j < tid) first = 0;
    }
    sh_order[rank] = tid;
    if (first) atomicAdd(&sh_nb, 1);
  }
  __syncthreads();
  const int nb = sh_nb;
  const int days = NROWS / nb;
  if (s == 0) {
    if (tid < NROWS) meta[tid] = sh_order[tid];
    if (tid == 0) meta[NROWS] = days;
  }
  const int lastRow = sh_order[s * days + days - 1];
  sh_last[tid] = seq[lastRow * LSEQ + tid];
  __syncthreads();
  if (tid < LSEQ - 1) {
    const float v = dm[(size_t)(sh_last[tid] - 1) * N_POI + (sh_last[tid + 1] - 1)];
    int si = (int)ceilf(2.0f * v);
    si = min(max(si, 0), 101);
    atomicAdd(&sh_cnt[si], 1);
  }
  __syncthreads();
  const float inv = 1.0f / (float)(LSEQ - 1);
  for (int k = tid; k < 128; k += 64) {
    const float wv = (k < NBINS) ? (float)sh_cnt[k] * inv : 0.0f;
    tfp[s * 128 + k] = wv;
    tbu[s * 128 + k] = bf16bits(wv);
  }
}

// ---------------------------------------------------------------------------
// K1 (fused): bucketize dm row (side='right' == floor(2v)+1) into uint8,
// build the row histogram in LDS (2-way split to halve atomic contention),
// then FUSE the per-sample rowsum: dot_s = sum_k h[k]*t_s[k], diag byte
// captured in-block, rbuf[s][row] = rsqrt(dot - t_s[bii] + 1).
// ---------------------------------------------------------------------------
__global__ __launch_bounds__(256) void k_bucket(const float* __restrict__ dm,
                                                const float* __restrict__ tfp,
                                                u8* __restrict__ bucket,
                                                float* __restrict__ rbuf) {
  const int row = blockIdx.x, tid = threadIdx.x;
  __shared__ int h[2][NBINS];
  __shared__ float tl[NB][NBINS];
  __shared__ int sh_bii;
  for (int k = tid; k < 2 * NBINS; k += 256) ((int*)h)[k] = 0;
  __syncthreads();
  const float4* drow = (const float4*)(dm + (size_t)row * N_POI);
  u32* brow = (u32*)(bucket + (size_t)row * N_POI);
  int* hp = h[tid >> 7];
  const int jdiag = row >> 2;
  for (int it = 0; it < 4; ++it) {
    const int j = it * 256 + tid;
    const float4 v = drow[j];
    const int b0 = min((int)(2.0f * v.x) + 1, 101);
    const int b1 = min((int)(2.0f * v.y) + 1, 101);
    const int b2 = min((int)(2.0f * v.z) + 1, 101);
    const int b3 = min((int)(2.0f * v.w) + 1, 101);
    atomicAdd(&hp[b0], 1); atomicAdd(&hp[b1], 1);
    atomicAdd(&hp[b2], 1); atomicAdd(&hp[b3], 1);
    const u32 pk = (u32)b0 | ((u32)b1 << 8) | ((u32)b2 << 16) | ((u32)b3 << 24);
    if (j == jdiag) sh_bii = (int)((pk >> (8 * (row & 3))) & 255u);
    brow[j] = pk;
  }
  // stage t tables (8 x 102 floats) while histogram finishes
  for (int idx = tid; idx < NB * NBINS; idx += 256)
    tl[idx / NBINS][idx % NBINS] = tfp[(idx / NBINS) * 128 + (idx % NBINS)];
  __syncthreads();
  for (int k = tid; k < NBINS; k += 256) h[0][k] += h[1][k];
  __syncthreads();
  // 32 lanes per sample: dot_s = sum_k h[k] * t_s[k]
  const int s = tid >> 5, ln = tid & 31;
  float dot = 0.f;
  for (int k = ln; k < NBINS; k += 32) dot += (float)h[0][k] * tl[s][k];
#pragma unroll
  for (int off = 16; off >= 1; off >>= 1) dot += __shfl_down(dot, off, 32);
  if (ln == 0) {
    const float ri = rsqrtf(dot - tl[s][sh_bii] + 1.0f);  // diag W[i,i]=1
    rbuf[s * N_POI + row] = ri;
  }
}

// ---------------------------------------------------------------------------
// K2b (slimmed): Y1^T[d][i] = bf16(r_i * poi_emb[i][d]). rbuf from k_bucket.
// ---------------------------------------------------------------------------
__global__ __launch_bounds__(256) void k_rows(const float* __restrict__ rbuf,
                                              const float* __restrict__ poi,
                                              ushort_t* __restrict__ y1t) {
  const int s = blockIdx.y;
  const int i = blockIdx.x * 256 + threadIdx.x;
  const float ri = rbuf[s * N_POI + i];
#pragma unroll 8
  for (int d = 0; d < 64; ++d) {
    const float pv = poi[(size_t)(i + 1) * 64 + d];  // poi_emb[i] = poi_weight[i+1]
    y1t[((size_t)s * 64 + d) * N_POI + i] = (ushort_t)bf16bits(ri * pv);
  }
}

// ---------------------------------------------------------------------------
// K3: GCN layer partial GEMM, SAMPLE-PAIR version. Each block computes TWO
// samples (s0=2g, s1=2g+1) over one K-chunk: the per-(row,k) bucket byte is
// gathered ONCE from a pair-packed LUT (trep[b] = t_s0[b] | t_s1[b]<<16),
// halving the trep ds_read_b32 count per sample -- the measured LDS-pipe
// bottleneck of the single-sample kernel (32 gathers = 186 of 281 LDS
// cyc/wave-tile). Both samples' Y^T tiles staged via global_load_lds
// (swizzled-source, linear dest), double-buffered, ONE vmcnt(0)+barrier per
// tile (proven round-3 sync; do not replace with register prefetch -- the
// compiler sinks it, rounds 1/2/4).
// Grid (32 rb, KC=6, 4 pairs) = 768 blocks -> 3 blocks/CU, 12 waves/CU.
// LDS 13KB trep + 32KB Ybuf = 45.8KB -> 3 blocks/CU.
// Epilogue stores raw bf16 partials for both samples.
// ---------------------------------------------------------------------------
__global__ __launch_bounds__(256, 3) void k_layer(
    const u8* __restrict__ bucket, const u32* __restrict__ tbu,
    const ushort_t* __restrict__ yin, ushort_t* __restrict__ part) {
  const int rb = blockIdx.x, kc = blockIdx.y, g = blockIdx.z;
  const int s0 = 2 * g, s1 = 2 * g + 1;
  const int tid = threadIdx.x;
  const int lane = tid & 63, w = tid >> 6;
  const int loff = tid & 31;

  __shared__ u32 trep[NBINS * 32];          // pair-packed LUT (s0 lo | s1 hi)
  __shared__ ushort_t Ybuf[2][2][64 * 64];  // [dbuf][sample], 8KB tiles

  const int gi0 = rb * 128;
  const int r0 = gi0 + w * 32 + (lane & 15);
  const u8* brow0 = bucket + (size_t)r0 * N_POI;
  const u8* brow1 = brow0 + (size_t)16 * N_POI;
  const int kq = (lane >> 4) * 8;

  const ushort_t* ybase0 = yin + (size_t)s0 * 64 * N_POI;
  const ushort_t* ybase1 = yin + (size_t)s1 * 64 * N_POI;

  // staging source (pre-swizzled column): thread covers LDS rows tid>>3 and
  // 32+(tid>>3), 16B at byte (tid&7)*16 of the 128B row, for BOTH samples.
  // perm(r) = (r&7) ^ ((r>>3)&1); LDS(r,b) holds Y(r, b ^ perm(r)<<4).
  const int d0s = tid >> 3, d1s = 32 + d0s;
  const int bly = (tid & 7) * 16;
  const int sw0 = bly ^ (((d0s & 7) ^ ((d0s >> 3) & 1)) << 4);
  const int sw1 = bly ^ (((d1s & 7) ^ ((d1s >> 3) & 1)) << 4);
  const char* g00 = (const char*)(ybase0 + (size_t)d0s * N_POI) + sw0;
  const char* g01 = (const char*)(ybase0 + (size_t)d1s * N_POI) + sw1;
  const char* g10 = (const char*)(ybase1 + (size_t)d0s * N_POI) + sw0;
  const char* g11 = (const char*)(ybase1 + (size_t)d1s * N_POI) + sw1;

  const int kt0 = (kc * 64) / KC, kt1 = ((kc + 1) * 64) / KC;  // 10-11 tiles

  uint2 bpA[4], bpB[4];

#define LOADB_(dst, ktv)                                   \
  {                                                        \
    const int _kb = (ktv) * 64;                            \
    dst[0] = *(const uint2*)(brow0 + _kb + kq);            \
    dst[1] = *(const uint2*)(brow0 + _kb + 32 + kq);       \
    dst[2] = *(const uint2*)(brow1 + _kb + kq);            \
    dst[3] = *(const uint2*)(brow1 + _kb + 32 + kq);       \
  }

#define STAGE_(bufi, ktv)                                  \
  {                                                        \
    const size_t _kb = (size_t)(ktv) * 128;                \
    char* _lb = (char*)&Ybuf[bufi][0][0] + tid * 16;       \
    gload16(_lb, g00 + _kb);                               \
    gload16(_lb + 4096, g01 + _kb);                        \
    gload16(_lb + 8192, g10 + _kb);                        \
    gload16(_lb + 12288, g11 + _kb);                       \
  }

  // prologue: stage first tile + first bucket bytes + pair-packed LUT
  STAGE_(0, kt0);
  LOADB_(bpA, kt0);
  for (int idx = tid; idx < NBINS * 32; idx += 256) {
    const int b = idx >> 5;
    trep[idx] = tbu[s0 * 128 + b] | (tbu[s1 * 128 + b] << 16);
  }

  f32x4 acc0[2][4], acc1[2][4];
#pragma unroll
  for (int mt = 0; mt < 2; ++mt)
#pragma unroll
    for (int nt = 0; nt < 4; ++nt) {
      acc0[mt][nt] = (f32x4){0.f, 0.f, 0.f, 0.f};
      acc1[mt][nt] = (f32x4){0.f, 0.f, 0.f, 0.f};
    }

  asm volatile("s_waitcnt vmcnt(0)" ::: "memory");
  __syncthreads();  // trep + stage(kt0) ready

#define BODY_(CB, PB, CUR)                                                     \
  {                                                                            \
    const int k0 = kt * 64;                                                    \
    if (kt + 1 < kt1) { STAGE_((CUR) ^ 1, kt + 1); LOADB_(PB, kt + 1); }       \
    bf16x8 af0[2][2], af1[2][2];                                               \
    _Pragma("unroll") for (int mt = 0; mt < 2; ++mt) {                         \
      _Pragma("unroll") for (int ks = 0; ks < 2; ++ks) {                       \
        const uint2 bb = CB[mt * 2 + ks];                                      \
        u32 tv[8];                                                             \
        _Pragma("unroll") for (int e = 0; e < 4; ++e) tv[e] =                  \
            trep[((bb.x >> (8 * e)) & 255u) * 32 + loff];                      \
        _Pragma("unroll") for (int e = 0; e < 4; ++e) tv[4 + e] =              \
            trep[((bb.y >> (8 * e)) & 255u) * 32 + loff];                      \
        const u32 de = (u32)(r0 + mt * 16 - (k0 + ks * 32 + kq));              \
        if (de < 8u) { /* diagonal A[i,i] = 1.0 for both samples */            \
          _Pragma("unroll") for (int e = 0; e < 8; ++e)                        \
              if (de == (u32)e) tv[e] = 0x3F803F80u;                           \
        }                                                                      \
        uint4 p0, p1;                                                          \
        p0.x = (tv[0] & 0xFFFFu) | (tv[1] << 16);                              \
        p0.y = (tv[2] & 0xFFFFu) | (tv[3] << 16);                              \
        p0.z = (tv[4] & 0xFFFFu) | (tv[5] << 16);                              \
        p0.w = (tv[6] & 0xFFFFu) | (tv[7] << 16);                              \
        p1.x = (tv[0] >> 16) | (tv[1] & 0xFFFF0000u);                          \
        p1.y = (tv[2] >> 16) | (tv[3] & 0xFFFF0000u);                          \
        p1.z = (tv[4] >> 16) | (tv[5] & 0xFFFF0000u);                          \
        p1.w = (tv[6] >> 16) | (tv[7] & 0xFFFF0000u);                          \
        union { uint4 u; bf16x8 v; } c0, c1;                                   \
        c0.u = p0; c1.u = p1;                                                  \
        af0[mt][ks] = c0.v; af1[mt][ks] = c1.v;                                \
      }                                                                        \
    }                                                                          \
    const char* _y0 = (const char*)&Ybuf[CUR][0][0];                           \
    const char* _y1 = (const char*)&Ybuf[CUR][1][0];                           \
    _Pragma("unroll") for (int ks = 0; ks < 2; ++ks) {                         \
      _Pragma("unroll") for (int nt = 0; nt < 4; ++nt) {                       \
        const int rY = nt * 16 + (lane & 15);                                  \
        const int pm = (rY & 7) ^ ((rY >> 3) & 1);                             \
        const int la = rY * 128 + (((ks * 4 + (lane >> 4)) ^ pm) << 4);        \
        union { uint4 u; bf16x8 v; } b0, b1;                                   \
        b0.u = *(const uint4*)(_y0 + la);                                      \
        b1.u = *(const uint4*)(_y1 + la);                                      \
        acc0[0][nt] = __builtin_amdgcn_mfma_f32_16x16x32_bf16(af0[0][ks], b0.v, \
                                                              acc0[0][nt], 0, 0, 0); \
        acc0[1][nt] = __builtin_amdgcn_mfma_f32_16x16x32_bf16(af0[1][ks], b0.v, \
                                                              acc0[1][nt], 0, 0, 0); \
        acc1[0][nt] = __builtin_amdgcn_mfma_f32_16x16x32_bf16(af1[0][ks], b1.v, \
                                                              acc1[0][nt], 0, 0, 0); \
        acc1[1][nt] = __builtin_amdgcn_mfma_f32_16x16x32_bf16(af1[1][ks], b1.v, \
                                                              acc1[1][nt], 0, 0, 0); \
      }                                                                        \
    }                                                                          \
    asm volatile("s_waitcnt vmcnt(0)" ::: "memory");                           \
    __syncthreads(); /* stage(kt+1) landed; buf[CUR] reads done for all */     \
  }

  int kt = kt0;
  while (true) {
    BODY_(bpA, bpB, 0);
    if (++kt >= kt1) break;
    BODY_(bpB, bpA, 1);
    if (++kt >= kt1) break;
  }

#undef BODY_
#undef STAGE_
#undef LOADB_

  // epilogue: raw bf16 partials, both samples.
  // C/D layout col = lane&15, row = (lane>>4)*4+reg
#pragma unroll
  for (int mt = 0; mt < 2; ++mt) {
#pragma unroll
    for (int e = 0; e < 4; ++e) {
      const int row = gi0 + w * 32 + mt * 16 + (lane >> 4) * 4 + e;
#pragma unroll
      for (int nt = 0; nt < 4; ++nt) {
        const int col = nt * 16 + (lane & 15);
        part[(((size_t)kc * NB + s0) * N_POI + row) * 64 + col] =
            (ushort_t)bf16bits(acc0[mt][nt][e]);
        part[(((size_t)kc * NB + s1) * N_POI + row) * 64 + col] =
            (ushort_t)bf16bits(acc1[mt][nt][e]);
      }
    }
  }
}

// ---------------------------------------------------------------------------
// K3b: reduce KC partials for LAYER 1 only: t = tanh(r*x),
// table = poi_emb + t (fp32); y2t^T = bf16(r*t) via LDS transpose.
// (Layer-2 reduce is folded into k_gather.)
// ---------------------------------------------------------------------------
__global__ __launch_bounds__(256) void k_reduce(
    const ushort_t* __restrict__ part, const float* __restrict__ rbuf,
    const float* __restrict__ poi, float* __restrict__ table,
    ushort_t* __restrict__ y2t) {
  const int it = blockIdx.x, s = blockIdx.y, tid = threadIdx.x;
  __shared__ ushort_t Tt[64 * 72];
#pragma unroll
  for (int j = 0; j < 2; ++j) {
    const int s2 = tid + j * 256;
    const int iloc = s2 >> 3, d0 = (s2 & 7) * 8;
    const int i = it * 64 + iloc;
    const size_t po = ((size_t)s * N_POI + i) * 64 + d0;
    float x[8] = {0.f, 0.f, 0.f, 0.f, 0.f, 0.f, 0.f, 0.f};
#pragma unroll
    for (int c = 0; c < KC; ++c) {
      uint4 p = *(const uint4*)(part + (size_t)c * NB * N_POI * 64 + po);
      const u32* a = (const u32*)&p;
#pragma unroll
      for (int q = 0; q < 4; ++q) {
        x[2 * q]     += __uint_as_float(a[q] << 16);
        x[2 * q + 1] += __uint_as_float(a[q] & 0xFFFF0000u);
      }
    }
    const float ri = rbuf[s * N_POI + i];
    float t[8];
#pragma unroll
    for (int e = 0; e < 8; ++e) t[e] = tanhf(ri * x[e]);
    float* trow = table + po;
    const float* prow = poi + (size_t)(i + 1) * 64 + d0;
    float4 pz0 = *(const float4*)prow;
    float4 pz1 = *(const float4*)(prow + 4);
    float4 o0 = {pz0.x + t[0], pz0.y + t[1], pz0.z + t[2], pz0.w + t[3]};
    float4 o1 = {pz1.x + t[4], pz1.y + t[5], pz1.z + t[6], pz1.w + t[7]};
    *(float4*)trow = o0;
    *(float4*)(trow + 4) = o1;
#pragma unroll
    for (int e = 0; e < 8; ++e)
      Tt[(d0 + e) * 72 + iloc] = (ushort_t)bf16bits(ri * t[e]);
  }
  __syncthreads();
  const int d = tid >> 2, i0 = (tid & 3) * 16;
  uint4 a = *(const uint4*)&Tt[d * 72 + i0];
  uint4 b = *(const uint4*)&Tt[d * 72 + i0 + 8];
  ushort_t* dst = y2t + ((size_t)s * 64 + d) * N_POI + it * 64 + i0;
  *(uint4*)dst = a;
  *(uint4*)(dst + 8) = b;
}

// ---------------------------------------------------------------------------
// K4: gather + fused layer-2 reduce:
// out[r][p][:] = (id==0) ? poi[0]*8
//              : (table_L1[g][id-1] + tanh(r * sum_kc part2)) * 8
// Only gathered rows (<=2048 of 32768) pay the reduce+tanh.
// ---------------------------------------------------------------------------
__global__ __launch_bounds__(256) void k_gather(const int* __restrict__ seq,
                                                const int* __restrict__ meta,
                                                const float* __restrict__ table,
                                                const float* __restrict__ poi,
                                                const ushort_t* __restrict__ part,
                                                const float* __restrict__ rbuf,
                                                float* __restrict__ out) {
  const int r = blockIdx.x;
  const int p = blockIdx.y * 4 + (threadIdx.x >> 6);
  const int d = threadIdx.x & 63;
  const int days = meta[NROWS];
  const int srcrow = meta[r];
  const int g = r / days;
  const int id = seq[srcrow * LSEQ + p];
  float v;
  if (id == 0) {
    v = poi[d];
  } else {
    const size_t po = ((size_t)g * N_POI + (id - 1)) * 64 + d;
    float x2 = 0.f;
#pragma unroll
    for (int c = 0; c < KC; ++c)
      x2 += b2f(part[(size_t)c * NB * N_POI * 64 + po]);
    v = table[po] + tanhf(rbuf[g * N_POI + (id - 1)] * x2);
  }
  out[((size_t)r * LSEQ + p) * 64 + d] = v * 8.0f;
}

// ---------------------------------------------------------------------------
extern "C" void kernel_launch(void* const* d_in, const int* in_sizes, int n_in,
                              void* d_out, int out_size, void* d_ws, size_t ws_size,
                              hipStream_t stream) {
  (void)in_sizes; (void)n_in; (void)out_size; (void)ws_size;
  const float* poi = (const float*)d_in[0];  // (4097, 64) f32
  const float* dm  = (const float*)d_in[1];  // (4096, 4096) f32
  const int*   seq = (const int*)d_in[2];    // (32, 64) i32
  const int*   ids = (const int*)d_in[3];    // (32,) i32
  // d_in[4]: GCN_layer_num (== 2 per setup_inputs)

  char* ws = (char*)d_ws;
  size_t off = 0;
  auto carve = [&](size_t bytes) {
    char* p = ws + off;
    off += (bytes + 255) & ~(size_t)255;
    return p;
  };
  u8*       bucket = (u8*)carve((size_t)N_POI * N_POI);            // 16.78 MB
  float*    tfp    = (float*)carve((size_t)NB * 128 * 4);
  u32*      tbu    = (u32*)carve((size_t)NB * 128 * 4);
  float*    rbuf   = (float*)carve((size_t)NB * N_POI * 4);
  // table (fp32, 8.39MB) aliases y1t (bf16, 4.19MB): y1t dead after k_layer L1;
  // table first written by k_reduce L1 (later in stream). y2t kept separate.
  float*    table  = (float*)carve((size_t)NB * N_POI * 64 * 4);     // 8.39 MB
  ushort_t* y1t    = (ushort_t*)table;
  ushort_t* y2t    = (ushort_t*)carve((size_t)NB * 64 * N_POI * 2);  // 4.19 MB
  ushort_t* part   = (ushort_t*)carve((size_t)KC * NB * N_POI * 64 * 2);  // 25.2 MB
  int*      meta   = (int*)carve(256);

  k_sample<<<NB, 64, 0, stream>>>(ids, seq, dm, tfp, tbu, meta);
  k_bucket<<<N_POI, 256, 0, stream>>>(dm, tfp, bucket, rbuf);
  k_rows<<<dim3(16, NB), 256, 0, stream>>>(rbuf, poi, y1t);
  k_layer<<<dim3(32, KC, 4), 256, 0, stream>>>(bucket, tbu, y1t, part);
  k_reduce<<<dim3(64, NB), 256, 0, stream>>>(part, rbuf, poi, table, y2t);
  k_layer<<<dim3(32, KC, 4), 256, 0, stream>>>(bucket, tbu, y2t, part);
  k_gather<<<dim3(NROWS, 16), 256, 0, stream>>>(seq, meta, table, poi, part, rbuf,
                                                (float*)d_out);
}